// Round 2
// baseline (4780.194 us; speedup 1.0000x reference)
//
#include <hip/hip_runtime.h>

#define DD 64
#define TPAD 66

static __device__ __forceinline__ float leaky(float x) {
    return x > 0.f ? x : 0.2f * x;
}

__global__ void concat_kernel(const float4* __restrict__ ue, const float4* __restrict__ ie,
                              float4* __restrict__ ego, int n_user4, int total4) {
    int idx = blockIdx.x * blockDim.x + threadIdx.x;
    if (idx >= total4) return;
    ego[idx] = (idx < n_user4) ? ue[idx] : ie[idx - n_user4];
}

__global__ void hist_kernel(const int* __restrict__ rows, int* __restrict__ counts, int nnz) {
    int e = blockIdx.x * blockDim.x + threadIdx.x;
    if (e < nnz) atomicAdd(&counts[rows[e]], 1);
}

__global__ void scan1_kernel(const int* __restrict__ counts, int* __restrict__ offsets,
                             int* __restrict__ blocksums, int n) {
    __shared__ int tmp[1024];
    int t = threadIdx.x;
    int g = blockIdx.x * 1024 + t;
    int x = (g < n) ? counts[g] : 0;
    tmp[t] = x;
    __syncthreads();
    for (int off = 1; off < 1024; off <<= 1) {
        int y = (t >= off) ? tmp[t - off] : 0;
        __syncthreads();
        tmp[t] += y;
        __syncthreads();
    }
    if (g < n) offsets[g + 1] = tmp[t];
    if (t == 1023) blocksums[blockIdx.x] = tmp[t];
    if (g == 0) offsets[0] = 0;
}

__global__ void scan2_kernel(int* blocksums, int nb) {
    __shared__ int tmp[256];
    int t = threadIdx.x;
    int v = (t < nb) ? blocksums[t] : 0;
    tmp[t] = v;
    __syncthreads();
    for (int off = 1; off < 256; off <<= 1) {
        int y = (t >= off) ? tmp[t - off] : 0;
        __syncthreads();
        tmp[t] += y;
        __syncthreads();
    }
    if (t < nb) blocksums[t] = tmp[t] - v;  // exclusive base per block
}

__global__ void scan3_kernel(const int* __restrict__ counts, int* __restrict__ offsets,
                             const int* __restrict__ blocksums, int* __restrict__ cursor, int n) {
    int g = blockIdx.x * 1024 + threadIdx.x;
    if (g < n) {
        int incl = offsets[g + 1] + blocksums[blockIdx.x];
        offsets[g + 1] = incl;
        cursor[g] = incl - counts[g];  // row start
    }
}

__global__ void scatter_kernel(const int* __restrict__ rows, const int* __restrict__ cols,
                               const float* __restrict__ vals, int* __restrict__ cursor,
                               int* __restrict__ csr_col, float* __restrict__ csr_val, int nnz) {
    int e = blockIdx.x * blockDim.x + threadIdx.x;
    if (e < nnz) {
        int r = rows[e];
        int p = atomicAdd(&cursor[r], 1);
        csr_col[p] = cols[e];
        csr_val[p] = vals[e];
    }
}

// wave-per-row SpMM: lane d accumulates element d of the row. No atomics,
// side fully overwritten (rows with zero edges write 0).
__global__ void spmm_kernel(const float* __restrict__ ego, const int* __restrict__ offsets,
                            const int* __restrict__ csr_col, const float* __restrict__ csr_val,
                            float* __restrict__ side, int n) {
    int wid = (blockIdx.x * blockDim.x + threadIdx.x) >> 6;
    int lane = threadIdx.x & 63;
    if (wid >= n) return;
    int s = offsets[wid], e = offsets[wid + 1];
    float acc = 0.f;
    for (int k = s; k < e; ++k) {
        acc += csr_val[k] * ego[csr_col[k] * DD + lane];
    }
    side[wid * DD + lane] = acc;
}

// ego_new = leaky(side@Wgc + bgc) + leaky((ego*side)@Wbi + bbi), in-place on ego.
// 32 nodes per 256-thread block; W + k-major S/P tiles in LDS; 2x4 micro-tile.
__global__ void __launch_bounds__(256) transform_kernel(
    const float* __restrict__ side, float* __restrict__ ego,
    const float* __restrict__ Wgc, const float* __restrict__ bgc,
    const float* __restrict__ Wbi, const float* __restrict__ bbi, int n) {
    __shared__ __align__(16) float sWg[DD * DD];
    __shared__ __align__(16) float sWb[DD * DD];
    __shared__ __align__(16) float sS[DD * TPAD];
    __shared__ __align__(16) float sP[DD * TPAD];
    int tid = threadIdx.x;
    int base = blockIdx.x * 32;

    for (int idx = tid * 4; idx < DD * DD; idx += 1024) {
        *(float4*)&sWg[idx] = *(const float4*)&Wgc[idx];
        *(float4*)&sWb[idx] = *(const float4*)&Wbi[idx];
    }
    // stage S and P = ego*side, transposed to k-major (pad 66 -> 2-way = free)
    for (int idx = tid; idx < 32 * DD; idx += 256) {
        int nl = idx >> 6, k = idx & 63;
        int node = base + nl;
        float sv = 0.f, ev = 0.f;
        if (node < n) {
            sv = side[node * DD + k];
            ev = ego[node * DD + k];
        }
        sS[k * TPAD + nl] = sv;
        sP[k * TPAD + nl] = ev * sv;
    }
    __syncthreads();

    int col4 = (tid & 15) * 4;
    int n2 = (tid >> 4) * 2;
    float acc1[2][4] = {{0.f, 0.f, 0.f, 0.f}, {0.f, 0.f, 0.f, 0.f}};
    float acc2[2][4] = {{0.f, 0.f, 0.f, 0.f}, {0.f, 0.f, 0.f, 0.f}};

#pragma unroll
    for (int k = 0; k < DD; ++k) {
        float2 sv = *(const float2*)&sS[k * TPAD + n2];
        float2 pv = *(const float2*)&sP[k * TPAD + n2];
        float4 wg = *(const float4*)&sWg[k * DD + col4];
        float4 wb = *(const float4*)&sWb[k * DD + col4];
        acc1[0][0] += sv.x * wg.x; acc1[0][1] += sv.x * wg.y;
        acc1[0][2] += sv.x * wg.z; acc1[0][3] += sv.x * wg.w;
        acc1[1][0] += sv.y * wg.x; acc1[1][1] += sv.y * wg.y;
        acc1[1][2] += sv.y * wg.z; acc1[1][3] += sv.y * wg.w;
        acc2[0][0] += pv.x * wb.x; acc2[0][1] += pv.x * wb.y;
        acc2[0][2] += pv.x * wb.z; acc2[0][3] += pv.x * wb.w;
        acc2[1][0] += pv.y * wb.x; acc2[1][1] += pv.y * wb.y;
        acc2[1][2] += pv.y * wb.z; acc2[1][3] += pv.y * wb.w;
    }

    float4 bg = *(const float4*)&bgc[col4];
    float4 bb = *(const float4*)&bbi[col4];
#pragma unroll
    for (int a = 0; a < 2; ++a) {
        int node = base + n2 + a;
        if (node < n) {
            float4 o;
            o.x = leaky(acc1[a][0] + bg.x) + leaky(acc2[a][0] + bb.x);
            o.y = leaky(acc1[a][1] + bg.y) + leaky(acc2[a][1] + bb.y);
            o.z = leaky(acc1[a][2] + bg.z) + leaky(acc2[a][2] + bb.z);
            o.w = leaky(acc1[a][3] + bg.w) + leaky(acc2[a][3] + bb.w);
            *(float4*)&ego[node * DD + col4] = o;
        }
    }
}

// one wave per output row; optional L2-normalize via butterfly shuffle reduce.
__global__ void gather_kernel(const float* __restrict__ ego, const int* __restrict__ u,
                              const int* __restrict__ ii, const int* __restrict__ jj,
                              float* __restrict__ out, int layer, int B, int n_users,
                              int normalize) {
    int wid = (blockIdx.x * blockDim.x + threadIdx.x) >> 6;
    int lane = threadIdx.x & 63;
    if (wid >= 3 * B) return;
    int arr = wid / B;
    int b = wid - arr * B;
    int node = (arr == 0) ? u[b] : ((arr == 1) ? n_users + ii[b] : n_users + jj[b]);
    float v = ego[node * DD + lane];
    if (normalize) {
        float ss = v * v;
#pragma unroll
        for (int m = 32; m; m >>= 1) ss += __shfl_xor(ss, m, 64);
        v /= fmaxf(sqrtf(ss), 1e-12f);
    }
    out[wid * 256 + layer * DD + lane] = v;
}

extern "C" void kernel_launch(void* const* d_in, const int* in_sizes, int n_in,
                              void* d_out, int out_size, void* d_ws, size_t ws_size,
                              hipStream_t stream) {
    const float* user_emb = (const float*)d_in[0];
    const float* item_emb = (const float*)d_in[1];
    const float* W_gc = (const float*)d_in[2];
    const float* b_gc = (const float*)d_in[3];
    const float* W_bi = (const float*)d_in[4];
    const float* b_bi = (const float*)d_in[5];
    const float* adj_vals = (const float*)d_in[6];
    const int* adj_rows = (const int*)d_in[7];
    const int* adj_cols = (const int*)d_in[8];
    const int* u = (const int*)d_in[9];
    const int* ii = (const int*)d_in[10];
    const int* jj = (const int*)d_in[11];
    float* out = (float*)d_out;

    const int D = DD;
    int n_users = in_sizes[0] / D;
    int n_items = in_sizes[1] / D;
    int n = n_users + n_items;
    int nnz = in_sizes[6];
    int B = in_sizes[9];
    int L = in_sizes[2] / (D * D);

    char* ws = (char*)d_ws;
    auto alloc = [&](size_t bytes) {
        char* p = ws;
        ws += (bytes + 255) & ~(size_t)255;
        return p;
    };
    float* ego = (float*)alloc((size_t)n * D * 4);
    float* side = (float*)alloc((size_t)n * D * 4);
    int* counts = (int*)alloc((size_t)n * 4);
    int* offsets = (int*)alloc((size_t)(n + 1) * 4);
    int* cursor = (int*)alloc((size_t)n * 4);
    int* blocksums = (int*)alloc(1024);
    int* csr_col = (int*)alloc((size_t)nnz * 4);
    float* csr_val = (float*)alloc((size_t)nnz * 4);

    // 1. ego = concat(user_emb, item_emb)
    int total4 = n * D / 4, nu4 = n_users * D / 4;
    concat_kernel<<<(total4 + 255) / 256, 256, 0, stream>>>(
        (const float4*)user_emb, (const float4*)item_emb, (float4*)ego, nu4, total4);

    // 2. layer-0 slice of the output (raw ego, no normalization)
    int grows = 3 * B;  // output rows
    gather_kernel<<<(grows + 3) / 4, 256, 0, stream>>>(ego, u, ii, jj, out, 0, B, n_users, 0);

    // 3. CSR build (graph is identical across layers)
    hipMemsetAsync(counts, 0, (size_t)n * 4, stream);
    hist_kernel<<<(nnz + 255) / 256, 256, 0, stream>>>(adj_rows, counts, nnz);
    int nblk = (n + 1023) / 1024;
    scan1_kernel<<<nblk, 1024, 0, stream>>>(counts, offsets, blocksums, n);
    scan2_kernel<<<1, 256, 0, stream>>>(blocksums, nblk);
    scan3_kernel<<<nblk, 1024, 0, stream>>>(counts, offsets, blocksums, cursor, n);
    scatter_kernel<<<(nnz + 255) / 256, 256, 0, stream>>>(adj_rows, adj_cols, adj_vals, cursor,
                                                          csr_col, csr_val, nnz);

    // 4. layers
    for (int l = 0; l < L; ++l) {
        spmm_kernel<<<(n + 3) / 4, 256, 0, stream>>>(ego, offsets, csr_col, csr_val, side, n);
        transform_kernel<<<(n + 31) / 32, 256, 0, stream>>>(
            side, ego, W_gc + (size_t)l * D * D, b_gc + (size_t)l * D,
            W_bi + (size_t)l * D * D, b_bi + (size_t)l * D, n);
        gather_kernel<<<(grows + 3) / 4, 256, 0, stream>>>(ego, u, ii, jj, out, l + 1, B,
                                                           n_users, 1);
    }
}

// Round 3
// 1285.803 us; speedup vs baseline: 3.7177x; 3.7177x over previous
//
#include <hip/hip_runtime.h>

#define DD 64
#define TPAD 66

static __device__ __forceinline__ float leaky(float x) {
    return x > 0.f ? x : 0.2f * x;
}

__global__ void concat_kernel(const float4* __restrict__ ue, const float4* __restrict__ ie,
                              float4* __restrict__ ego, int n_user4, int total4) {
    int idx = blockIdx.x * blockDim.x + threadIdx.x;
    if (idx >= total4) return;
    ego[idx] = (idx < n_user4) ? ue[idx] : ie[idx - n_user4];
}

__global__ void hist_kernel(const int* __restrict__ rows, int* __restrict__ counts, int nnz) {
    int e = blockIdx.x * blockDim.x + threadIdx.x;
    if (e < nnz) atomicAdd(&counts[rows[e]], 1);
}

__global__ void scan1_kernel(const int* __restrict__ counts, int* __restrict__ offsets,
                             int* __restrict__ blocksums, int n) {
    __shared__ int tmp[1024];
    int t = threadIdx.x;
    int g = blockIdx.x * 1024 + t;
    int x = (g < n) ? counts[g] : 0;
    tmp[t] = x;
    __syncthreads();
    for (int off = 1; off < 1024; off <<= 1) {
        int y = (t >= off) ? tmp[t - off] : 0;
        __syncthreads();
        tmp[t] += y;
        __syncthreads();
    }
    if (g < n) offsets[g + 1] = tmp[t];
    if (t == 1023) blocksums[blockIdx.x] = tmp[t];
    if (g == 0) offsets[0] = 0;
}

__global__ void scan2_kernel(int* blocksums, int nb) {
    __shared__ int tmp[256];
    int t = threadIdx.x;
    int v = (t < nb) ? blocksums[t] : 0;
    tmp[t] = v;
    __syncthreads();
    for (int off = 1; off < 256; off <<= 1) {
        int y = (t >= off) ? tmp[t - off] : 0;
        __syncthreads();
        tmp[t] += y;
        __syncthreads();
    }
    if (t < nb) blocksums[t] = tmp[t] - v;  // exclusive base per block
}

__global__ void scan3_kernel(const int* __restrict__ counts, int* __restrict__ offsets,
                             const int* __restrict__ blocksums, int* __restrict__ cursor, int n) {
    int g = blockIdx.x * 1024 + threadIdx.x;
    if (g < n) {
        int incl = offsets[g + 1] + blocksums[blockIdx.x];
        offsets[g + 1] = incl;
        cursor[g] = incl - counts[g];  // row start
    }
}

__global__ void scatter_kernel(const int* __restrict__ rows, const int* __restrict__ cols,
                               const float* __restrict__ vals, int* __restrict__ cursor,
                               int* __restrict__ csr_col, float* __restrict__ csr_val, int nnz) {
    int e = blockIdx.x * blockDim.x + threadIdx.x;
    if (e < nnz) {
        int r = rows[e];
        int p = atomicAdd(&cursor[r], 1);
        csr_col[p] = cols[e];
        csr_val[p] = vals[e];
    }
}

// wave-per-row SpMM: lane d accumulates element d of the row. No atomics,
// side fully overwritten (rows with zero edges write 0).
__global__ void spmm_kernel(const float* __restrict__ ego, const int* __restrict__ offsets,
                            const int* __restrict__ csr_col, const float* __restrict__ csr_val,
                            float* __restrict__ side, int n) {
    int wid = (blockIdx.x * blockDim.x + threadIdx.x) >> 6;
    int lane = threadIdx.x & 63;
    if (wid >= n) return;
    int s = offsets[wid], e = offsets[wid + 1];
    float acc = 0.f;
    for (int k = s; k < e; ++k) {
        acc += csr_val[k] * ego[csr_col[k] * DD + lane];
    }
    side[wid * DD + lane] = acc;
}

// ego_new = leaky(side@Wgc + bgc) + leaky((ego*side)@Wbi + bbi), in-place on ego.
// 32 nodes per 256-thread block; W + k-major S/P tiles in LDS; 2x4 micro-tile.
// unroll 4: full unroll made the compiler hoist ~768 ds_read results ->
// 256 VGPRs + scratch spills (4.15 GB HBM traffic/dispatch, R2 counters).
// launch_bounds(256,4) caps allocator at 128 VGPRs.
__global__ void __launch_bounds__(256, 4) transform_kernel(
    const float* __restrict__ side, float* __restrict__ ego,
    const float* __restrict__ Wgc, const float* __restrict__ bgc,
    const float* __restrict__ Wbi, const float* __restrict__ bbi, int n) {
    __shared__ __align__(16) float sWg[DD * DD];
    __shared__ __align__(16) float sWb[DD * DD];
    __shared__ __align__(16) float sS[DD * TPAD];
    __shared__ __align__(16) float sP[DD * TPAD];
    int tid = threadIdx.x;
    int base = blockIdx.x * 32;

    for (int idx = tid * 4; idx < DD * DD; idx += 1024) {
        *(float4*)&sWg[idx] = *(const float4*)&Wgc[idx];
        *(float4*)&sWb[idx] = *(const float4*)&Wbi[idx];
    }
    // stage S and P = ego*side, transposed to k-major (pad 66 -> 2-way = free)
    for (int idx = tid; idx < 32 * DD; idx += 256) {
        int nl = idx >> 6, k = idx & 63;
        int node = base + nl;
        float sv = 0.f, ev = 0.f;
        if (node < n) {
            sv = side[node * DD + k];
            ev = ego[node * DD + k];
        }
        sS[k * TPAD + nl] = sv;
        sP[k * TPAD + nl] = ev * sv;
    }
    __syncthreads();

    int col4 = (tid & 15) * 4;
    int n2 = (tid >> 4) * 2;
    float acc1[2][4] = {{0.f, 0.f, 0.f, 0.f}, {0.f, 0.f, 0.f, 0.f}};
    float acc2[2][4] = {{0.f, 0.f, 0.f, 0.f}, {0.f, 0.f, 0.f, 0.f}};

#pragma unroll 4
    for (int k = 0; k < DD; ++k) {
        float2 sv = *(const float2*)&sS[k * TPAD + n2];
        float2 pv = *(const float2*)&sP[k * TPAD + n2];
        float4 wg = *(const float4*)&sWg[k * DD + col4];
        float4 wb = *(const float4*)&sWb[k * DD + col4];
        acc1[0][0] += sv.x * wg.x; acc1[0][1] += sv.x * wg.y;
        acc1[0][2] += sv.x * wg.z; acc1[0][3] += sv.x * wg.w;
        acc1[1][0] += sv.y * wg.x; acc1[1][1] += sv.y * wg.y;
        acc1[1][2] += sv.y * wg.z; acc1[1][3] += sv.y * wg.w;
        acc2[0][0] += pv.x * wb.x; acc2[0][1] += pv.x * wb.y;
        acc2[0][2] += pv.x * wb.z; acc2[0][3] += pv.x * wb.w;
        acc2[1][0] += pv.y * wb.x; acc2[1][1] += pv.y * wb.y;
        acc2[1][2] += pv.y * wb.z; acc2[1][3] += pv.y * wb.w;
    }

    float4 bg = *(const float4*)&bgc[col4];
    float4 bb = *(const float4*)&bbi[col4];
#pragma unroll
    for (int a = 0; a < 2; ++a) {
        int node = base + n2 + a;
        if (node < n) {
            float4 o;
            o.x = leaky(acc1[a][0] + bg.x) + leaky(acc2[a][0] + bb.x);
            o.y = leaky(acc1[a][1] + bg.y) + leaky(acc2[a][1] + bb.y);
            o.z = leaky(acc1[a][2] + bg.z) + leaky(acc2[a][2] + bb.z);
            o.w = leaky(acc1[a][3] + bg.w) + leaky(acc2[a][3] + bb.w);
            *(float4*)&ego[node * DD + col4] = o;
        }
    }
}

// one wave per output row; optional L2-normalize via butterfly shuffle reduce.
__global__ void gather_kernel(const float* __restrict__ ego, const int* __restrict__ u,
                              const int* __restrict__ ii, const int* __restrict__ jj,
                              float* __restrict__ out, int layer, int B, int n_users,
                              int normalize) {
    int wid = (blockIdx.x * blockDim.x + threadIdx.x) >> 6;
    int lane = threadIdx.x & 63;
    if (wid >= 3 * B) return;
    int arr = wid / B;
    int b = wid - arr * B;
    int node = (arr == 0) ? u[b] : ((arr == 1) ? n_users + ii[b] : n_users + jj[b]);
    float v = ego[node * DD + lane];
    if (normalize) {
        float ss = v * v;
#pragma unroll
        for (int m = 32; m; m >>= 1) ss += __shfl_xor(ss, m, 64);
        v /= fmaxf(sqrtf(ss), 1e-12f);
    }
    out[wid * 256 + layer * DD + lane] = v;
}

extern "C" void kernel_launch(void* const* d_in, const int* in_sizes, int n_in,
                              void* d_out, int out_size, void* d_ws, size_t ws_size,
                              hipStream_t stream) {
    const float* user_emb = (const float*)d_in[0];
    const float* item_emb = (const float*)d_in[1];
    const float* W_gc = (const float*)d_in[2];
    const float* b_gc = (const float*)d_in[3];
    const float* W_bi = (const float*)d_in[4];
    const float* b_bi = (const float*)d_in[5];
    const float* adj_vals = (const float*)d_in[6];
    const int* adj_rows = (const int*)d_in[7];
    const int* adj_cols = (const int*)d_in[8];
    const int* u = (const int*)d_in[9];
    const int* ii = (const int*)d_in[10];
    const int* jj = (const int*)d_in[11];
    float* out = (float*)d_out;

    const int D = DD;
    int n_users = in_sizes[0] / D;
    int n_items = in_sizes[1] / D;
    int n = n_users + n_items;
    int nnz = in_sizes[6];
    int B = in_sizes[9];
    int L = in_sizes[2] / (D * D);

    char* ws = (char*)d_ws;
    auto alloc = [&](size_t bytes) {
        char* p = ws;
        ws += (bytes + 255) & ~(size_t)255;
        return p;
    };
    float* ego = (float*)alloc((size_t)n * D * 4);
    float* side = (float*)alloc((size_t)n * D * 4);
    int* counts = (int*)alloc((size_t)n * 4);
    int* offsets = (int*)alloc((size_t)(n + 1) * 4);
    int* cursor = (int*)alloc((size_t)n * 4);
    int* blocksums = (int*)alloc(1024);
    int* csr_col = (int*)alloc((size_t)nnz * 4);
    float* csr_val = (float*)alloc((size_t)nnz * 4);

    // 1. ego = concat(user_emb, item_emb)
    int total4 = n * D / 4, nu4 = n_users * D / 4;
    concat_kernel<<<(total4 + 255) / 256, 256, 0, stream>>>(
        (const float4*)user_emb, (const float4*)item_emb, (float4*)ego, nu4, total4);

    // 2. layer-0 slice of the output (raw ego, no normalization)
    int grows = 3 * B;  // output rows
    gather_kernel<<<(grows + 3) / 4, 256, 0, stream>>>(ego, u, ii, jj, out, 0, B, n_users, 0);

    // 3. CSR build (graph is identical across layers)
    hipMemsetAsync(counts, 0, (size_t)n * 4, stream);
    hist_kernel<<<(nnz + 255) / 256, 256, 0, stream>>>(adj_rows, counts, nnz);
    int nblk = (n + 1023) / 1024;
    scan1_kernel<<<nblk, 1024, 0, stream>>>(counts, offsets, blocksums, n);
    scan2_kernel<<<1, 256, 0, stream>>>(blocksums, nblk);
    scan3_kernel<<<nblk, 1024, 0, stream>>>(counts, offsets, blocksums, cursor, n);
    scatter_kernel<<<(nnz + 255) / 256, 256, 0, stream>>>(adj_rows, adj_cols, adj_vals, cursor,
                                                          csr_col, csr_val, nnz);

    // 4. layers
    for (int l = 0; l < L; ++l) {
        spmm_kernel<<<(n + 3) / 4, 256, 0, stream>>>(ego, offsets, csr_col, csr_val, side, n);
        transform_kernel<<<(n + 31) / 32, 256, 0, stream>>>(
            side, ego, W_gc + (size_t)l * D * D, b_gc + (size_t)l * D,
            W_bi + (size_t)l * D * D, b_bi + (size_t)l * D, n);
        gather_kernel<<<(grows + 3) / 4, 256, 0, stream>>>(ego, u, ii, jj, out, l + 1, B,
                                                           n_users, 1);
    }
}

// Round 4
// 920.230 us; speedup vs baseline: 5.1946x; 1.3973x over previous
//
#include <hip/hip_runtime.h>

#define DD 64
#define TPAD 66

static __device__ __forceinline__ float leaky(float x) {
    return x > 0.f ? x : 0.2f * x;
}

__global__ void concat_kernel(const float4* __restrict__ ue, const float4* __restrict__ ie,
                              float4* __restrict__ ego, int n_user4, int total4) {
    int idx = blockIdx.x * blockDim.x + threadIdx.x;
    if (idx >= total4) return;
    ego[idx] = (idx < n_user4) ? ue[idx] : ie[idx - n_user4];
}

__global__ void hist_kernel(const int* __restrict__ rows, int* __restrict__ counts, int nnz) {
    int e = blockIdx.x * blockDim.x + threadIdx.x;
    if (e < nnz) atomicAdd(&counts[rows[e]], 1);
}

__global__ void scan1_kernel(const int* __restrict__ counts, int* __restrict__ offsets,
                             int* __restrict__ blocksums, int n) {
    __shared__ int tmp[1024];
    int t = threadIdx.x;
    int g = blockIdx.x * 1024 + t;
    int x = (g < n) ? counts[g] : 0;
    tmp[t] = x;
    __syncthreads();
    for (int off = 1; off < 1024; off <<= 1) {
        int y = (t >= off) ? tmp[t - off] : 0;
        __syncthreads();
        tmp[t] += y;
        __syncthreads();
    }
    if (g < n) offsets[g + 1] = tmp[t];
    if (t == 1023) blocksums[blockIdx.x] = tmp[t];
    if (g == 0) offsets[0] = 0;
}

__global__ void scan2_kernel(int* blocksums, int nb) {
    __shared__ int tmp[256];
    int t = threadIdx.x;
    int v = (t < nb) ? blocksums[t] : 0;
    tmp[t] = v;
    __syncthreads();
    for (int off = 1; off < 256; off <<= 1) {
        int y = (t >= off) ? tmp[t - off] : 0;
        __syncthreads();
        tmp[t] += y;
        __syncthreads();
    }
    if (t < nb) blocksums[t] = tmp[t] - v;  // exclusive base per block
}

__global__ void scan3_kernel(const int* __restrict__ counts, int* __restrict__ offsets,
                             const int* __restrict__ blocksums, int* __restrict__ cursor, int n) {
    int g = blockIdx.x * 1024 + threadIdx.x;
    if (g < n) {
        int incl = offsets[g + 1] + blocksums[blockIdx.x];
        offsets[g + 1] = incl;
        cursor[g] = incl - counts[g];  // row start
    }
}

// packs {col, bitcast(val)} -> one 8B scattered store per edge instead of two 4B
__global__ void scatter_kernel(const int* __restrict__ rows, const int* __restrict__ cols,
                               const float* __restrict__ vals, int* __restrict__ cursor,
                               int2* __restrict__ csr_cv, int nnz) {
    int e = blockIdx.x * blockDim.x + threadIdx.x;
    if (e < nnz) {
        int r = rows[e];
        int p = atomicAdd(&cursor[r], 1);
        int2 cv;
        cv.x = cols[e];
        cv.y = __float_as_int(vals[e]);
        csr_cv[p] = cv;
    }
}

// SpMM: 4 rows per wave, 16 lanes per row, float4 per lane.
// One dwordx4 gather instruction moves 4x256B useful data; edge loop unrolled
// x4 so 4 gathers are in flight per wave (R3 version had 1 -> latency-bound,
// VALUBusy 16%, 1.5 TB/s).
__global__ void spmm_kernel(const float4* __restrict__ ego4, const int* __restrict__ offsets,
                            const int2* __restrict__ csr_cv, float4* __restrict__ side4, int n) {
    int wid = (blockIdx.x * blockDim.x + threadIdx.x) >> 6;
    int lane = threadIdx.x & 63;
    int sub = lane >> 4;   // which of 4 rows this subgroup handles
    int l16 = lane & 15;   // float4 slot within the row
    int row = wid * 4 + sub;
    if (row >= n) return;
    int s = offsets[row], e = offsets[row + 1];
    float4 acc = {0.f, 0.f, 0.f, 0.f};
    int k = s;
    for (; k + 4 <= e; k += 4) {
        int2 cv0 = csr_cv[k];
        int2 cv1 = csr_cv[k + 1];
        int2 cv2 = csr_cv[k + 2];
        int2 cv3 = csr_cv[k + 3];
        float4 g0 = ego4[cv0.x * 16 + l16];
        float4 g1 = ego4[cv1.x * 16 + l16];
        float4 g2 = ego4[cv2.x * 16 + l16];
        float4 g3 = ego4[cv3.x * 16 + l16];
        float v0 = __int_as_float(cv0.y);
        float v1 = __int_as_float(cv1.y);
        float v2 = __int_as_float(cv2.y);
        float v3 = __int_as_float(cv3.y);
        acc.x += v0 * g0.x; acc.y += v0 * g0.y; acc.z += v0 * g0.z; acc.w += v0 * g0.w;
        acc.x += v1 * g1.x; acc.y += v1 * g1.y; acc.z += v1 * g1.z; acc.w += v1 * g1.w;
        acc.x += v2 * g2.x; acc.y += v2 * g2.y; acc.z += v2 * g2.z; acc.w += v2 * g2.w;
        acc.x += v3 * g3.x; acc.y += v3 * g3.y; acc.z += v3 * g3.z; acc.w += v3 * g3.w;
    }
    for (; k < e; ++k) {
        int2 cv = csr_cv[k];
        float4 g = ego4[cv.x * 16 + l16];
        float v = __int_as_float(cv.y);
        acc.x += v * g.x; acc.y += v * g.y; acc.z += v * g.z; acc.w += v * g.w;
    }
    side4[row * 16 + l16] = acc;
}

// ego_new = leaky(side@Wgc + bgc) + leaky((ego*side)@Wbi + bbi), in-place on ego.
// 32 nodes per 256-thread block; W + k-major S/P tiles in LDS; 2x4 micro-tile.
// unroll 4: full unroll made the compiler hoist ~768 ds_read results ->
// 256 VGPRs + scratch spills (4.15 GB HBM traffic/dispatch, R2 counters).
// launch_bounds(256,4) caps allocator at 128 VGPRs.
__global__ void __launch_bounds__(256, 4) transform_kernel(
    const float* __restrict__ side, float* __restrict__ ego,
    const float* __restrict__ Wgc, const float* __restrict__ bgc,
    const float* __restrict__ Wbi, const float* __restrict__ bbi, int n) {
    __shared__ __align__(16) float sWg[DD * DD];
    __shared__ __align__(16) float sWb[DD * DD];
    __shared__ __align__(16) float sS[DD * TPAD];
    __shared__ __align__(16) float sP[DD * TPAD];
    int tid = threadIdx.x;
    int base = blockIdx.x * 32;

    for (int idx = tid * 4; idx < DD * DD; idx += 1024) {
        *(float4*)&sWg[idx] = *(const float4*)&Wgc[idx];
        *(float4*)&sWb[idx] = *(const float4*)&Wbi[idx];
    }
    // stage S and P = ego*side, transposed to k-major (pad 66 -> 2-way = free)
    for (int idx = tid; idx < 32 * DD; idx += 256) {
        int nl = idx >> 6, k = idx & 63;
        int node = base + nl;
        float sv = 0.f, ev = 0.f;
        if (node < n) {
            sv = side[node * DD + k];
            ev = ego[node * DD + k];
        }
        sS[k * TPAD + nl] = sv;
        sP[k * TPAD + nl] = ev * sv;
    }
    __syncthreads();

    int col4 = (tid & 15) * 4;
    int n2 = (tid >> 4) * 2;
    float acc1[2][4] = {{0.f, 0.f, 0.f, 0.f}, {0.f, 0.f, 0.f, 0.f}};
    float acc2[2][4] = {{0.f, 0.f, 0.f, 0.f}, {0.f, 0.f, 0.f, 0.f}};

#pragma unroll 4
    for (int k = 0; k < DD; ++k) {
        float2 sv = *(const float2*)&sS[k * TPAD + n2];
        float2 pv = *(const float2*)&sP[k * TPAD + n2];
        float4 wg = *(const float4*)&sWg[k * DD + col4];
        float4 wb = *(const float4*)&sWb[k * DD + col4];
        acc1[0][0] += sv.x * wg.x; acc1[0][1] += sv.x * wg.y;
        acc1[0][2] += sv.x * wg.z; acc1[0][3] += sv.x * wg.w;
        acc1[1][0] += sv.y * wg.x; acc1[1][1] += sv.y * wg.y;
        acc1[1][2] += sv.y * wg.z; acc1[1][3] += sv.y * wg.w;
        acc2[0][0] += pv.x * wb.x; acc2[0][1] += pv.x * wb.y;
        acc2[0][2] += pv.x * wb.z; acc2[0][3] += pv.x * wb.w;
        acc2[1][0] += pv.y * wb.x; acc2[1][1] += pv.y * wb.y;
        acc2[1][2] += pv.y * wb.z; acc2[1][3] += pv.y * wb.w;
    }

    float4 bg = *(const float4*)&bgc[col4];
    float4 bb = *(const float4*)&bbi[col4];
#pragma unroll
    for (int a = 0; a < 2; ++a) {
        int node = base + n2 + a;
        if (node < n) {
            float4 o;
            o.x = leaky(acc1[a][0] + bg.x) + leaky(acc2[a][0] + bb.x);
            o.y = leaky(acc1[a][1] + bg.y) + leaky(acc2[a][1] + bb.y);
            o.z = leaky(acc1[a][2] + bg.z) + leaky(acc2[a][2] + bb.z);
            o.w = leaky(acc1[a][3] + bg.w) + leaky(acc2[a][3] + bb.w);
            *(float4*)&ego[node * DD + col4] = o;
        }
    }
}

// one wave per output row; optional L2-normalize via butterfly shuffle reduce.
__global__ void gather_kernel(const float* __restrict__ ego, const int* __restrict__ u,
                              const int* __restrict__ ii, const int* __restrict__ jj,
                              float* __restrict__ out, int layer, int B, int n_users,
                              int normalize) {
    int wid = (blockIdx.x * blockDim.x + threadIdx.x) >> 6;
    int lane = threadIdx.x & 63;
    if (wid >= 3 * B) return;
    int arr = wid / B;
    int b = wid - arr * B;
    int node = (arr == 0) ? u[b] : ((arr == 1) ? n_users + ii[b] : n_users + jj[b]);
    float v = ego[node * DD + lane];
    if (normalize) {
        float ss = v * v;
#pragma unroll
        for (int m = 32; m; m >>= 1) ss += __shfl_xor(ss, m, 64);
        v /= fmaxf(sqrtf(ss), 1e-12f);
    }
    out[wid * 256 + layer * DD + lane] = v;
}

extern "C" void kernel_launch(void* const* d_in, const int* in_sizes, int n_in,
                              void* d_out, int out_size, void* d_ws, size_t ws_size,
                              hipStream_t stream) {
    const float* user_emb = (const float*)d_in[0];
    const float* item_emb = (const float*)d_in[1];
    const float* W_gc = (const float*)d_in[2];
    const float* b_gc = (const float*)d_in[3];
    const float* W_bi = (const float*)d_in[4];
    const float* b_bi = (const float*)d_in[5];
    const float* adj_vals = (const float*)d_in[6];
    const int* adj_rows = (const int*)d_in[7];
    const int* adj_cols = (const int*)d_in[8];
    const int* u = (const int*)d_in[9];
    const int* ii = (const int*)d_in[10];
    const int* jj = (const int*)d_in[11];
    float* out = (float*)d_out;

    const int D = DD;
    int n_users = in_sizes[0] / D;
    int n_items = in_sizes[1] / D;
    int n = n_users + n_items;
    int nnz = in_sizes[6];
    int B = in_sizes[9];
    int L = in_sizes[2] / (D * D);

    char* ws = (char*)d_ws;
    auto alloc = [&](size_t bytes) {
        char* p = ws;
        ws += (bytes + 255) & ~(size_t)255;
        return p;
    };
    float* ego = (float*)alloc((size_t)n * D * 4);
    float* side = (float*)alloc((size_t)n * D * 4);
    int* counts = (int*)alloc((size_t)n * 4);
    int* offsets = (int*)alloc((size_t)(n + 1) * 4);
    int* cursor = (int*)alloc((size_t)n * 4);
    int* blocksums = (int*)alloc(1024);
    int2* csr_cv = (int2*)alloc((size_t)nnz * 8);

    // 1. ego = concat(user_emb, item_emb)
    int total4 = n * D / 4, nu4 = n_users * D / 4;
    concat_kernel<<<(total4 + 255) / 256, 256, 0, stream>>>(
        (const float4*)user_emb, (const float4*)item_emb, (float4*)ego, nu4, total4);

    // 2. layer-0 slice of the output (raw ego, no normalization)
    int grows = 3 * B;  // output rows
    gather_kernel<<<(grows + 3) / 4, 256, 0, stream>>>(ego, u, ii, jj, out, 0, B, n_users, 0);

    // 3. CSR build (graph is identical across layers)
    hipMemsetAsync(counts, 0, (size_t)n * 4, stream);
    hist_kernel<<<(nnz + 255) / 256, 256, 0, stream>>>(adj_rows, counts, nnz);
    int nblk = (n + 1023) / 1024;
    scan1_kernel<<<nblk, 1024, 0, stream>>>(counts, offsets, blocksums, n);
    scan2_kernel<<<1, 256, 0, stream>>>(blocksums, nblk);
    scan3_kernel<<<nblk, 1024, 0, stream>>>(counts, offsets, blocksums, cursor, n);
    scatter_kernel<<<(nnz + 255) / 256, 256, 0, stream>>>(adj_rows, adj_cols, adj_vals, cursor,
                                                          csr_cv, nnz);

    // 4. layers
    for (int l = 0; l < L; ++l) {
        // 4 rows per wave -> ceil(n/4) waves -> x64 threads
        int spmm_waves = (n + 3) / 4;
        int spmm_blocks = (spmm_waves * 64 + 255) / 256;
        spmm_kernel<<<spmm_blocks, 256, 0, stream>>>(
            (const float4*)ego, offsets, csr_cv, (float4*)side, n);
        transform_kernel<<<(n + 31) / 32, 256, 0, stream>>>(
            side, ego, W_gc + (size_t)l * D * D, b_gc + (size_t)l * D,
            W_bi + (size_t)l * D * D, b_bi + (size_t)l * D, n);
        gather_kernel<<<(grows + 3) / 4, 256, 0, stream>>>(ego, u, ii, jj, out, l + 1, B,
                                                           n_users, 1);
    }
}

// Round 5
// 808.166 us; speedup vs baseline: 5.9149x; 1.1387x over previous
//
#include <hip/hip_runtime.h>

#define DD 64
#define TPAD 66
#define RB 64          // rows per bucket
#define RB_SHIFT 6
#define CAP 1280       // LDS-sorted edge capacity per bucket (avg 1024, +8 sigma)
#define NBLKA 128      // blocks in the two bucketing passes (must match)
#define BMAX 4096      // max buckets (n <= BMAX*RB = 262144, also the 18-bit col limit)
#define COLM 0x3FFFF

static __device__ __forceinline__ float leaky(float x) {
    return x > 0.f ? x : 0.2f * x;
}

__global__ void concat_kernel(const float4* __restrict__ ue, const float4* __restrict__ ie,
                              float4* __restrict__ ego, int n_user4, int total4) {
    int idx = blockIdx.x * blockDim.x + threadIdx.x;
    if (idx >= total4) return;
    ego[idx] = (idx < n_user4) ? ue[idx] : ie[idx - n_user4];
}

// pass A: per-(bucket, block) histogram via LDS — no global atomics
__global__ void bhist_kernel(const int* __restrict__ rows, int* __restrict__ counts, int nnz,
                             int nbuckets) {
    __shared__ int h[BMAX];
    int tid = threadIdx.x, blk = blockIdx.x;
    for (int i = tid; i < nbuckets; i += 256) h[i] = 0;
    __syncthreads();
    int chunk = (nnz + NBLKA - 1) / NBLKA;
    int lo = blk * chunk, hi = min(nnz, lo + chunk);
    for (int e = lo + tid; e < hi; e += 256) atomicAdd(&h[rows[e] >> RB_SHIFT], 1);
    __syncthreads();
    for (int i = tid; i < nbuckets; i += 256) counts[i * NBLKA + blk] = h[i];
}

__global__ void scan1_kernel(const int* __restrict__ counts, int* __restrict__ offsets,
                             int* __restrict__ blocksums, int n) {
    __shared__ int tmp[1024];
    int t = threadIdx.x;
    int g = blockIdx.x * 1024 + t;
    int x = (g < n) ? counts[g] : 0;
    tmp[t] = x;
    __syncthreads();
    for (int off = 1; off < 1024; off <<= 1) {
        int y = (t >= off) ? tmp[t - off] : 0;
        __syncthreads();
        tmp[t] += y;
        __syncthreads();
    }
    if (g < n) offsets[g + 1] = tmp[t];
    if (t == 1023) blocksums[blockIdx.x] = tmp[t];
    if (g == 0) offsets[0] = 0;
}

__global__ void scan2_kernel(int* blocksums, int nb) {
    __shared__ int tmp[1024];
    int t = threadIdx.x;
    int v = (t < nb) ? blocksums[t] : 0;
    tmp[t] = v;
    __syncthreads();
    for (int off = 1; off < 1024; off <<= 1) {
        int y = (t >= off) ? tmp[t - off] : 0;
        __syncthreads();
        tmp[t] += y;
        __syncthreads();
    }
    if (t < nb) blocksums[t] = tmp[t] - v;  // exclusive base per block
}

__global__ void scan3_kernel(int* __restrict__ offsets, const int* __restrict__ blocksums,
                             int n) {
    int g = blockIdx.x * 1024 + threadIdx.x;
    if (g < n) offsets[g + 1] += blocksums[blockIdx.x];
}

// pass B: write each edge into its block-private contiguous slot range per bucket.
// One block's slots per bucket are consecutive and written from one CU -> 64B
// lines fill inside that XCD's L2 -> no write amplification (R4 scatter: 149MB
// WRITE for 19MB payload). Zero global atomics.
__global__ void bscatter_kernel(const int* __restrict__ rows, const int* __restrict__ cols,
                                const float* __restrict__ vals, const int* __restrict__ offsets,
                                int2* __restrict__ csr_cv, int nnz, int nbuckets) {
    __shared__ int cur[BMAX];
    int tid = threadIdx.x, blk = blockIdx.x;
    for (int i = tid; i < nbuckets; i += 256) cur[i] = offsets[i * NBLKA + blk];
    __syncthreads();
    int chunk = (nnz + NBLKA - 1) / NBLKA;
    int lo = blk * chunk, hi = min(nnz, lo + chunk);
    for (int e = lo + tid; e < hi; e += 256) {
        int r = rows[e];
        int p = atomicAdd(&cur[r >> RB_SHIFT], 1);
        int2 cv;
        cv.x = ((r & (RB - 1)) << 18) | cols[e];  // row_low(6b) | col(18b)
        cv.y = __float_as_int(vals[e]);
        csr_cv[p] = cv;
    }
}

// SpMM: one bucket (64 rows, ~1024 edges) per 256-thread block.
// Counting-sort the bucket's edges by row in LDS, then 4 rows/wave x float4
// gather loop (4 gathers in flight) as in R4.
__global__ void __launch_bounds__(256) spmm_bucket_kernel(
    const float4* __restrict__ ego4, const int* __restrict__ offsets,
    const int2* __restrict__ csr_cv, float4* __restrict__ side4, int n) {
    __shared__ int2 sorted[CAP];
    __shared__ int hist[RB];
    __shared__ int rowoff[RB + 1];
    __shared__ int cur[RB];
    int tid = threadIdx.x;
    int b = blockIdx.x;
    int s = offsets[b * NBLKA];
    int e = offsets[(b + 1) * NBLKA];  // offsets[flat] == nnz, valid for last bucket
    int m = min(e - s, CAP);

    if (tid < RB) hist[tid] = 0;
    __syncthreads();
    for (int k = s + tid; k < s + m; k += 256)
        atomicAdd(&hist[((unsigned)csr_cv[k].x) >> 18], 1);
    __syncthreads();
    // inclusive scan of hist in place
    for (int off = 1; off < RB; off <<= 1) {
        int v = 0;
        if (tid < RB && tid >= off) v = hist[tid - off];
        __syncthreads();
        if (tid < RB) hist[tid] += v;
        __syncthreads();
    }
    if (tid < RB) rowoff[tid + 1] = hist[tid];
    if (tid == 0) rowoff[0] = 0;
    __syncthreads();
    if (tid < RB) cur[tid] = rowoff[tid];
    __syncthreads();
    for (int k = s + tid; k < s + m; k += 256) {
        int2 cv = csr_cv[k];
        int p = atomicAdd(&cur[((unsigned)cv.x) >> 18], 1);
        sorted[p] = cv;
    }
    __syncthreads();

    int w = tid >> 6, lane = tid & 63, sub = lane >> 4, l16 = lane & 15;
#pragma unroll
    for (int itr = 0; itr < RB / 16; ++itr) {
        int rl = w * (RB / 4) + itr * 4 + sub;
        int ks = rowoff[rl], ke = rowoff[rl + 1];
        float4 acc = {0.f, 0.f, 0.f, 0.f};
        int k = ks;
        for (; k + 4 <= ke; k += 4) {
            int2 c0 = sorted[k];
            int2 c1 = sorted[k + 1];
            int2 c2 = sorted[k + 2];
            int2 c3 = sorted[k + 3];
            float4 g0 = ego4[(c0.x & COLM) * 16 + l16];
            float4 g1 = ego4[(c1.x & COLM) * 16 + l16];
            float4 g2 = ego4[(c2.x & COLM) * 16 + l16];
            float4 g3 = ego4[(c3.x & COLM) * 16 + l16];
            float v0 = __int_as_float(c0.y), v1 = __int_as_float(c1.y);
            float v2 = __int_as_float(c2.y), v3 = __int_as_float(c3.y);
            acc.x += v0 * g0.x; acc.y += v0 * g0.y; acc.z += v0 * g0.z; acc.w += v0 * g0.w;
            acc.x += v1 * g1.x; acc.y += v1 * g1.y; acc.z += v1 * g1.z; acc.w += v1 * g1.w;
            acc.x += v2 * g2.x; acc.y += v2 * g2.y; acc.z += v2 * g2.z; acc.w += v2 * g2.w;
            acc.x += v3 * g3.x; acc.y += v3 * g3.y; acc.z += v3 * g3.z; acc.w += v3 * g3.w;
        }
        for (; k < ke; ++k) {
            int2 cv = sorted[k];
            float4 g = ego4[(cv.x & COLM) * 16 + l16];
            float v = __int_as_float(cv.y);
            acc.x += v * g.x; acc.y += v * g.y; acc.z += v * g.z; acc.w += v * g.w;
        }
        int row = b * RB + rl;
        if (row < n) side4[row * 16 + l16] = acc;
    }

    // overflow fallback (statistically never: CAP = avg + 8 sigma) — correctness only
    if (e - s > CAP) {
        __syncthreads();
        const float* ego = (const float*)ego4;
        float* side = (float*)side4;
        for (int k = s + CAP + tid; k < e; k += 256) {
            int2 cv = csr_cv[k];
            int row = b * RB + (int)(((unsigned)cv.x) >> 18);
            int col = cv.x & COLM;
            float v = __int_as_float(cv.y);
            if (row < n)
                for (int d = 0; d < DD; ++d)
                    atomicAdd(&side[row * DD + d], v * ego[col * DD + d]);
        }
    }
}

// ego_new = leaky(side@Wgc + bgc) + leaky((ego*side)@Wbi + bbi), in-place on ego.
// unroll 4 + launch_bounds(256,4): full unroll blew VGPRs to 256 + spills (R2).
__global__ void __launch_bounds__(256, 4) transform_kernel(
    const float* __restrict__ side, float* __restrict__ ego,
    const float* __restrict__ Wgc, const float* __restrict__ bgc,
    const float* __restrict__ Wbi, const float* __restrict__ bbi, int n) {
    __shared__ __align__(16) float sWg[DD * DD];
    __shared__ __align__(16) float sWb[DD * DD];
    __shared__ __align__(16) float sS[DD * TPAD];
    __shared__ __align__(16) float sP[DD * TPAD];
    int tid = threadIdx.x;
    int base = blockIdx.x * 32;

    for (int idx = tid * 4; idx < DD * DD; idx += 1024) {
        *(float4*)&sWg[idx] = *(const float4*)&Wgc[idx];
        *(float4*)&sWb[idx] = *(const float4*)&Wbi[idx];
    }
    for (int idx = tid; idx < 32 * DD; idx += 256) {
        int nl = idx >> 6, k = idx & 63;
        int node = base + nl;
        float sv = 0.f, ev = 0.f;
        if (node < n) {
            sv = side[node * DD + k];
            ev = ego[node * DD + k];
        }
        sS[k * TPAD + nl] = sv;
        sP[k * TPAD + nl] = ev * sv;
    }
    __syncthreads();

    int col4 = (tid & 15) * 4;
    int n2 = (tid >> 4) * 2;
    float acc1[2][4] = {{0.f, 0.f, 0.f, 0.f}, {0.f, 0.f, 0.f, 0.f}};
    float acc2[2][4] = {{0.f, 0.f, 0.f, 0.f}, {0.f, 0.f, 0.f, 0.f}};

#pragma unroll 4
    for (int k = 0; k < DD; ++k) {
        float2 sv = *(const float2*)&sS[k * TPAD + n2];
        float2 pv = *(const float2*)&sP[k * TPAD + n2];
        float4 wg = *(const float4*)&sWg[k * DD + col4];
        float4 wb = *(const float4*)&sWb[k * DD + col4];
        acc1[0][0] += sv.x * wg.x; acc1[0][1] += sv.x * wg.y;
        acc1[0][2] += sv.x * wg.z; acc1[0][3] += sv.x * wg.w;
        acc1[1][0] += sv.y * wg.x; acc1[1][1] += sv.y * wg.y;
        acc1[1][2] += sv.y * wg.z; acc1[1][3] += sv.y * wg.w;
        acc2[0][0] += pv.x * wb.x; acc2[0][1] += pv.x * wb.y;
        acc2[0][2] += pv.x * wb.z; acc2[0][3] += pv.x * wb.w;
        acc2[1][0] += pv.y * wb.x; acc2[1][1] += pv.y * wb.y;
        acc2[1][2] += pv.y * wb.z; acc2[1][3] += pv.y * wb.w;
    }

    float4 bg = *(const float4*)&bgc[col4];
    float4 bb = *(const float4*)&bbi[col4];
#pragma unroll
    for (int a = 0; a < 2; ++a) {
        int node = base + n2 + a;
        if (node < n) {
            float4 o;
            o.x = leaky(acc1[a][0] + bg.x) + leaky(acc2[a][0] + bb.x);
            o.y = leaky(acc1[a][1] + bg.y) + leaky(acc2[a][1] + bb.y);
            o.z = leaky(acc1[a][2] + bg.z) + leaky(acc2[a][2] + bb.z);
            o.w = leaky(acc1[a][3] + bg.w) + leaky(acc2[a][3] + bb.w);
            *(float4*)&ego[node * DD + col4] = o;
        }
    }
}

__global__ void gather_kernel(const float* __restrict__ ego, const int* __restrict__ u,
                              const int* __restrict__ ii, const int* __restrict__ jj,
                              float* __restrict__ out, int layer, int B, int n_users,
                              int normalize) {
    int wid = (blockIdx.x * blockDim.x + threadIdx.x) >> 6;
    int lane = threadIdx.x & 63;
    if (wid >= 3 * B) return;
    int arr = wid / B;
    int b = wid - arr * B;
    int node = (arr == 0) ? u[b] : ((arr == 1) ? n_users + ii[b] : n_users + jj[b]);
    float v = ego[node * DD + lane];
    if (normalize) {
        float ss = v * v;
#pragma unroll
        for (int m = 32; m; m >>= 1) ss += __shfl_xor(ss, m, 64);
        v /= fmaxf(sqrtf(ss), 1e-12f);
    }
    out[wid * 256 + layer * DD + lane] = v;
}

extern "C" void kernel_launch(void* const* d_in, const int* in_sizes, int n_in,
                              void* d_out, int out_size, void* d_ws, size_t ws_size,
                              hipStream_t stream) {
    const float* user_emb = (const float*)d_in[0];
    const float* item_emb = (const float*)d_in[1];
    const float* W_gc = (const float*)d_in[2];
    const float* b_gc = (const float*)d_in[3];
    const float* W_bi = (const float*)d_in[4];
    const float* b_bi = (const float*)d_in[5];
    const float* adj_vals = (const float*)d_in[6];
    const int* adj_rows = (const int*)d_in[7];
    const int* adj_cols = (const int*)d_in[8];
    const int* u = (const int*)d_in[9];
    const int* ii = (const int*)d_in[10];
    const int* jj = (const int*)d_in[11];
    float* out = (float*)d_out;

    const int D = DD;
    int n_users = in_sizes[0] / D;
    int n_items = in_sizes[1] / D;
    int n = n_users + n_items;
    int nnz = in_sizes[6];
    int B = in_sizes[9];
    int L = in_sizes[2] / (D * D);

    int nbuckets = (n + RB - 1) / RB;      // 2344
    int flat = nbuckets * NBLKA;           // 300032

    char* ws = (char*)d_ws;
    auto alloc = [&](size_t bytes) {
        char* p = ws;
        ws += (bytes + 255) & ~(size_t)255;
        return p;
    };
    float* ego = (float*)alloc((size_t)n * D * 4);
    float* side = (float*)alloc((size_t)n * D * 4);
    int* counts = (int*)alloc((size_t)flat * 4);
    int* offsets = (int*)alloc((size_t)(flat + 1) * 4);
    int* blocksums = (int*)alloc(4096);
    int2* csr_cv = (int2*)alloc((size_t)nnz * 8);

    // 1. ego = concat(user_emb, item_emb)
    int total4 = n * D / 4, nu4 = n_users * D / 4;
    concat_kernel<<<(total4 + 255) / 256, 256, 0, stream>>>(
        (const float4*)user_emb, (const float4*)item_emb, (float4*)ego, nu4, total4);

    // 2. layer-0 slice of the output (raw ego, no normalization)
    int grows = 3 * B;
    gather_kernel<<<(grows + 3) / 4, 256, 0, stream>>>(ego, u, ii, jj, out, 0, B, n_users, 0);

    // 3. bucketed CSR build: hist -> scan(flat) -> coalesced-stream scatter
    bhist_kernel<<<NBLKA, 256, 0, stream>>>(adj_rows, counts, nnz, nbuckets);
    int nblk1 = (flat + 1023) / 1024;
    scan1_kernel<<<nblk1, 1024, 0, stream>>>(counts, offsets, blocksums, flat);
    scan2_kernel<<<1, 1024, 0, stream>>>(blocksums, nblk1);
    scan3_kernel<<<nblk1, 1024, 0, stream>>>(offsets, blocksums, flat);
    bscatter_kernel<<<NBLKA, 256, 0, stream>>>(adj_rows, adj_cols, adj_vals, offsets, csr_cv,
                                               nnz, nbuckets);

    // 4. layers
    for (int l = 0; l < L; ++l) {
        spmm_bucket_kernel<<<nbuckets, 256, 0, stream>>>(
            (const float4*)ego, offsets, csr_cv, (float4*)side, n);
        transform_kernel<<<(n + 31) / 32, 256, 0, stream>>>(
            side, ego, W_gc + (size_t)l * D * D, b_gc + (size_t)l * D,
            W_bi + (size_t)l * D * D, b_bi + (size_t)l * D, n);
        gather_kernel<<<(grows + 3) / 4, 256, 0, stream>>>(ego, u, ii, jj, out, l + 1, B,
                                                           n_users, 1);
    }
}

// Round 6
// 733.126 us; speedup vs baseline: 6.5203x; 1.1024x over previous
//
#include <hip/hip_runtime.h>

#define DD 64
#define TPAD 66
#define RB 256         // rows per bucket
#define RB_SHIFT 8
#define CAP 4608       // LDS-sorted edge capacity per bucket (avg 4096, +8 sigma)
#define NBLKA 512      // blocks in the two bucketing passes (pow2; must match)
#define NBLKA_SHIFT 9
#define BMAX 1024      // max buckets (n <= BMAX*RB, col fits 18 bits)
#define COLM 0x3FFFF

static __device__ __forceinline__ float leaky(float x) {
    return x > 0.f ? x : 0.2f * x;
}

__global__ void concat_kernel(const float4* __restrict__ ue, const float4* __restrict__ ie,
                              float4* __restrict__ ego, int n_user4, int total4) {
    int idx = blockIdx.x * blockDim.x + threadIdx.x;
    if (idx >= total4) return;
    ego[idx] = (idx < n_user4) ? ue[idx] : ie[idx - n_user4];
}

// pass A: per-(bucket, block) histogram via LDS — no global atomics.
// counts stored block-major (transposed) so the 586 writes per block coalesce.
__global__ void bhist_kernel(const int* __restrict__ rows, int* __restrict__ counts_t, int nnz,
                             int nbuckets) {
    __shared__ int h[BMAX];
    int tid = threadIdx.x, blk = blockIdx.x;
    for (int i = tid; i < nbuckets; i += 256) h[i] = 0;
    __syncthreads();
    int chunk = (nnz + NBLKA - 1) / NBLKA;
    int lo = blk * chunk, hi = min(nnz, lo + chunk);
    for (int e = lo + tid; e < hi; e += 256) atomicAdd(&h[rows[e] >> RB_SHIFT], 1);
    __syncthreads();
    for (int i = tid; i < nbuckets; i += 256) counts_t[blk * nbuckets + i] = h[i];
}

// scan over flat order f = bucket*NBLKA + blk, reading transposed counts.
__global__ void scan1_kernel(const int* __restrict__ counts_t, int* __restrict__ offsets,
                             int* __restrict__ blocksums, int flat, int nbuckets) {
    __shared__ int tmp[1024];
    int t = threadIdx.x;
    int g = blockIdx.x * 1024 + t;
    int x = 0;
    if (g < flat) {
        int i = g >> NBLKA_SHIFT, blk = g & (NBLKA - 1);
        x = counts_t[blk * nbuckets + i];
    }
    tmp[t] = x;
    __syncthreads();
    for (int off = 1; off < 1024; off <<= 1) {
        int y = (t >= off) ? tmp[t - off] : 0;
        __syncthreads();
        tmp[t] += y;
        __syncthreads();
    }
    if (g < flat) offsets[g + 1] = tmp[t];
    if (t == 1023) blocksums[blockIdx.x] = tmp[t];
    if (g == 0) offsets[0] = 0;
}

__global__ void scan2_kernel(int* blocksums, int nb) {
    __shared__ int tmp[1024];
    int t = threadIdx.x;
    int v = (t < nb) ? blocksums[t] : 0;
    tmp[t] = v;
    __syncthreads();
    for (int off = 1; off < 1024; off <<= 1) {
        int y = (t >= off) ? tmp[t - off] : 0;
        __syncthreads();
        tmp[t] += y;
        __syncthreads();
    }
    if (t < nb) blocksums[t] = tmp[t] - v;  // exclusive base per block
}

__global__ void scan3_kernel(int* __restrict__ offsets, const int* __restrict__ blocksums,
                             int n) {
    int g = blockIdx.x * 1024 + threadIdx.x;
    if (g < n) offsets[g + 1] += blocksums[blockIdx.x];
}

// pass B: write each edge into its block-private contiguous slot range per bucket.
// NBLKA=512 -> 2 blocks/CU on all 256 CUs (R5: 128 blocks = half the CUs idle,
// store-issue-bound at 111us). Segment = 8 edges = 64B, ~1 line.
__global__ void bscatter_kernel(const int* __restrict__ rows, const int* __restrict__ cols,
                                const float* __restrict__ vals, const int* __restrict__ offsets,
                                int2* __restrict__ csr_cv, int nnz, int nbuckets) {
    __shared__ int cur[BMAX];
    int tid = threadIdx.x, blk = blockIdx.x;
    for (int i = tid; i < nbuckets; i += 256) cur[i] = offsets[i * NBLKA + blk];
    __syncthreads();
    int chunk = (nnz + NBLKA - 1) / NBLKA;
    int lo = blk * chunk, hi = min(nnz, lo + chunk);
    for (int e = lo + tid; e < hi; e += 256) {
        int r = rows[e];
        int p = atomicAdd(&cur[r >> RB_SHIFT], 1);
        int2 cv;
        cv.x = ((r & (RB - 1)) << 18) | cols[e];  // row_low(8b) | col(18b)
        cv.y = __float_as_int(vals[e]);
        csr_cv[p] = cv;
    }
}

// SpMM: one bucket (256 rows, ~4096 edges) per 256-thread block.
// Counting-sort the bucket's edges by row in LDS, then 4 rows/wave x float4
// gather loop (4 gathers in flight).
__global__ void __launch_bounds__(256) spmm_bucket_kernel(
    const float4* __restrict__ ego4, const int* __restrict__ offsets,
    const int2* __restrict__ csr_cv, float4* __restrict__ side4, int n) {
    __shared__ int2 sorted[CAP];
    __shared__ int hist[RB];
    __shared__ int rowoff[RB + 1];
    __shared__ int cur[RB];
    int tid = threadIdx.x;
    int b = blockIdx.x;
    int s = offsets[b * NBLKA];
    int e = offsets[(b + 1) * NBLKA];  // offsets[flat] == nnz for the last bucket
    int m = min(e - s, CAP);

    hist[tid] = 0;
    __syncthreads();
    for (int k = s + tid; k < s + m; k += 256)
        atomicAdd(&hist[((unsigned)csr_cv[k].x) >> 18], 1);
    __syncthreads();
    // inclusive scan of hist (256 entries, 256 threads)
    for (int off = 1; off < RB; off <<= 1) {
        int v = (tid >= off) ? hist[tid - off] : 0;
        __syncthreads();
        hist[tid] += v;
        __syncthreads();
    }
    rowoff[tid + 1] = hist[tid];
    if (tid == 0) rowoff[0] = 0;
    __syncthreads();
    cur[tid] = rowoff[tid];
    __syncthreads();
    for (int k = s + tid; k < s + m; k += 256) {
        int2 cv = csr_cv[k];
        int p = atomicAdd(&cur[((unsigned)cv.x) >> 18], 1);
        sorted[p] = cv;
    }
    __syncthreads();

    int w = tid >> 6, lane = tid & 63, sub = lane >> 4, l16 = lane & 15;
#pragma unroll
    for (int itr = 0; itr < RB / 16; ++itr) {
        int rl = w * (RB / 4) + itr * 4 + sub;
        int ks = rowoff[rl], ke = rowoff[rl + 1];
        float4 acc = {0.f, 0.f, 0.f, 0.f};
        int k = ks;
        for (; k + 4 <= ke; k += 4) {
            int2 c0 = sorted[k];
            int2 c1 = sorted[k + 1];
            int2 c2 = sorted[k + 2];
            int2 c3 = sorted[k + 3];
            float4 g0 = ego4[(c0.x & COLM) * 16 + l16];
            float4 g1 = ego4[(c1.x & COLM) * 16 + l16];
            float4 g2 = ego4[(c2.x & COLM) * 16 + l16];
            float4 g3 = ego4[(c3.x & COLM) * 16 + l16];
            float v0 = __int_as_float(c0.y), v1 = __int_as_float(c1.y);
            float v2 = __int_as_float(c2.y), v3 = __int_as_float(c3.y);
            acc.x += v0 * g0.x; acc.y += v0 * g0.y; acc.z += v0 * g0.z; acc.w += v0 * g0.w;
            acc.x += v1 * g1.x; acc.y += v1 * g1.y; acc.z += v1 * g1.z; acc.w += v1 * g1.w;
            acc.x += v2 * g2.x; acc.y += v2 * g2.y; acc.z += v2 * g2.z; acc.w += v2 * g2.w;
            acc.x += v3 * g3.x; acc.y += v3 * g3.y; acc.z += v3 * g3.z; acc.w += v3 * g3.w;
        }
        for (; k < ke; ++k) {
            int2 cv = sorted[k];
            float4 g = ego4[(cv.x & COLM) * 16 + l16];
            float v = __int_as_float(cv.y);
            acc.x += v * g.x; acc.y += v * g.y; acc.z += v * g.z; acc.w += v * g.w;
        }
        int row = b * RB + rl;
        if (row < n) side4[row * 16 + l16] = acc;
    }

    // overflow fallback (statistically never: CAP = avg + 8 sigma) — correctness only
    if (e - s > CAP) {
        __syncthreads();
        const float* ego = (const float*)ego4;
        float* side = (float*)side4;
        for (int k = s + CAP + tid; k < e; k += 256) {
            int2 cv = csr_cv[k];
            int row = b * RB + (int)(((unsigned)cv.x) >> 18);
            int col = cv.x & COLM;
            float v = __int_as_float(cv.y);
            if (row < n)
                for (int d = 0; d < DD; ++d)
                    atomicAdd(&side[row * DD + d], v * ego[col * DD + d]);
        }
    }
}

// ego_new = leaky(side@Wgc + bgc) + leaky((ego*side)@Wbi + bbi), in-place on ego.
// unroll 4 + launch_bounds(256,4): full unroll blew VGPRs to 256 + spills (R2).
__global__ void __launch_bounds__(256, 4) transform_kernel(
    const float* __restrict__ side, float* __restrict__ ego,
    const float* __restrict__ Wgc, const float* __restrict__ bgc,
    const float* __restrict__ Wbi, const float* __restrict__ bbi, int n) {
    __shared__ __align__(16) float sWg[DD * DD];
    __shared__ __align__(16) float sWb[DD * DD];
    __shared__ __align__(16) float sS[DD * TPAD];
    __shared__ __align__(16) float sP[DD * TPAD];
    int tid = threadIdx.x;
    int base = blockIdx.x * 32;

    for (int idx = tid * 4; idx < DD * DD; idx += 1024) {
        *(float4*)&sWg[idx] = *(const float4*)&Wgc[idx];
        *(float4*)&sWb[idx] = *(const float4*)&Wbi[idx];
    }
    for (int idx = tid; idx < 32 * DD; idx += 256) {
        int nl = idx >> 6, k = idx & 63;
        int node = base + nl;
        float sv = 0.f, ev = 0.f;
        if (node < n) {
            sv = side[node * DD + k];
            ev = ego[node * DD + k];
        }
        sS[k * TPAD + nl] = sv;
        sP[k * TPAD + nl] = ev * sv;
    }
    __syncthreads();

    int col4 = (tid & 15) * 4;
    int n2 = (tid >> 4) * 2;
    float acc1[2][4] = {{0.f, 0.f, 0.f, 0.f}, {0.f, 0.f, 0.f, 0.f}};
    float acc2[2][4] = {{0.f, 0.f, 0.f, 0.f}, {0.f, 0.f, 0.f, 0.f}};

#pragma unroll 4
    for (int k = 0; k < DD; ++k) {
        float2 sv = *(const float2*)&sS[k * TPAD + n2];
        float2 pv = *(const float2*)&sP[k * TPAD + n2];
        float4 wg = *(const float4*)&sWg[k * DD + col4];
        float4 wb = *(const float4*)&sWb[k * DD + col4];
        acc1[0][0] += sv.x * wg.x; acc1[0][1] += sv.x * wg.y;
        acc1[0][2] += sv.x * wg.z; acc1[0][3] += sv.x * wg.w;
        acc1[1][0] += sv.y * wg.x; acc1[1][1] += sv.y * wg.y;
        acc1[1][2] += sv.y * wg.z; acc1[1][3] += sv.y * wg.w;
        acc2[0][0] += pv.x * wb.x; acc2[0][1] += pv.x * wb.y;
        acc2[0][2] += pv.x * wb.z; acc2[0][3] += pv.x * wb.w;
        acc2[1][0] += pv.y * wb.x; acc2[1][1] += pv.y * wb.y;
        acc2[1][2] += pv.y * wb.z; acc2[1][3] += pv.y * wb.w;
    }

    float4 bg = *(const float4*)&bgc[col4];
    float4 bb = *(const float4*)&bbi[col4];
#pragma unroll
    for (int a = 0; a < 2; ++a) {
        int node = base + n2 + a;
        if (node < n) {
            float4 o;
            o.x = leaky(acc1[a][0] + bg.x) + leaky(acc2[a][0] + bb.x);
            o.y = leaky(acc1[a][1] + bg.y) + leaky(acc2[a][1] + bb.y);
            o.z = leaky(acc1[a][2] + bg.z) + leaky(acc2[a][2] + bb.z);
            o.w = leaky(acc1[a][3] + bg.w) + leaky(acc2[a][3] + bb.w);
            *(float4*)&ego[node * DD + col4] = o;
        }
    }
}

__global__ void gather_kernel(const float* __restrict__ ego, const int* __restrict__ u,
                              const int* __restrict__ ii, const int* __restrict__ jj,
                              float* __restrict__ out, int layer, int B, int n_users,
                              int normalize) {
    int wid = (blockIdx.x * blockDim.x + threadIdx.x) >> 6;
    int lane = threadIdx.x & 63;
    if (wid >= 3 * B) return;
    int arr = wid / B;
    int b = wid - arr * B;
    int node = (arr == 0) ? u[b] : ((arr == 1) ? n_users + ii[b] : n_users + jj[b]);
    float v = ego[node * DD + lane];
    if (normalize) {
        float ss = v * v;
#pragma unroll
        for (int m = 32; m; m >>= 1) ss += __shfl_xor(ss, m, 64);
        v /= fmaxf(sqrtf(ss), 1e-12f);
    }
    out[wid * 256 + layer * DD + lane] = v;
}

extern "C" void kernel_launch(void* const* d_in, const int* in_sizes, int n_in,
                              void* d_out, int out_size, void* d_ws, size_t ws_size,
                              hipStream_t stream) {
    const float* user_emb = (const float*)d_in[0];
    const float* item_emb = (const float*)d_in[1];
    const float* W_gc = (const float*)d_in[2];
    const float* b_gc = (const float*)d_in[3];
    const float* W_bi = (const float*)d_in[4];
    const float* b_bi = (const float*)d_in[5];
    const float* adj_vals = (const float*)d_in[6];
    const int* adj_rows = (const int*)d_in[7];
    const int* adj_cols = (const int*)d_in[8];
    const int* u = (const int*)d_in[9];
    const int* ii = (const int*)d_in[10];
    const int* jj = (const int*)d_in[11];
    float* out = (float*)d_out;

    const int D = DD;
    int n_users = in_sizes[0] / D;
    int n_items = in_sizes[1] / D;
    int n = n_users + n_items;
    int nnz = in_sizes[6];
    int B = in_sizes[9];
    int L = in_sizes[2] / (D * D);

    int nbuckets = (n + RB - 1) / RB;      // 586
    int flat = nbuckets * NBLKA;           // 300032

    char* ws = (char*)d_ws;
    auto alloc = [&](size_t bytes) {
        char* p = ws;
        ws += (bytes + 255) & ~(size_t)255;
        return p;
    };
    float* ego = (float*)alloc((size_t)n * D * 4);
    float* side = (float*)alloc((size_t)n * D * 4);
    int* counts_t = (int*)alloc((size_t)flat * 4);
    int* offsets = (int*)alloc((size_t)(flat + 1) * 4);
    int* blocksums = (int*)alloc(4096);
    int2* csr_cv = (int2*)alloc((size_t)nnz * 8);

    // 1. ego = concat(user_emb, item_emb)
    int total4 = n * D / 4, nu4 = n_users * D / 4;
    concat_kernel<<<(total4 + 255) / 256, 256, 0, stream>>>(
        (const float4*)user_emb, (const float4*)item_emb, (float4*)ego, nu4, total4);

    // 2. layer-0 slice of the output (raw ego, no normalization)
    int grows = 3 * B;
    gather_kernel<<<(grows + 3) / 4, 256, 0, stream>>>(ego, u, ii, jj, out, 0, B, n_users, 0);

    // 3. bucketed CSR build: hist -> scan(flat) -> coalesced-stream scatter
    bhist_kernel<<<NBLKA, 256, 0, stream>>>(adj_rows, counts_t, nnz, nbuckets);
    int nblk1 = (flat + 1023) / 1024;
    scan1_kernel<<<nblk1, 1024, 0, stream>>>(counts_t, offsets, blocksums, flat, nbuckets);
    scan2_kernel<<<1, 1024, 0, stream>>>(blocksums, nblk1);
    scan3_kernel<<<nblk1, 1024, 0, stream>>>(offsets, blocksums, flat);
    bscatter_kernel<<<NBLKA, 256, 0, stream>>>(adj_rows, adj_cols, adj_vals, offsets, csr_cv,
                                               nnz, nbuckets);

    // 4. layers
    for (int l = 0; l < L; ++l) {
        spmm_bucket_kernel<<<nbuckets, 256, 0, stream>>>(
            (const float4*)ego, offsets, csr_cv, (float4*)side, n);
        transform_kernel<<<(n + 31) / 32, 256, 0, stream>>>(
            side, ego, W_gc + (size_t)l * D * D, b_gc + (size_t)l * D,
            W_bi + (size_t)l * D * D, b_bi + (size_t)l * D, n);
        gather_kernel<<<(grows + 3) / 4, 256, 0, stream>>>(ego, u, ii, jj, out, l + 1, B,
                                                           n_users, 1);
    }
}